// Round 2
// baseline (1842.288 us; speedup 1.0000x reference)
//
#include <hip/hip_runtime.h>
#include <hip/hip_bf16.h>
#include <cstdint>
#include <cstddef>

static inline size_t align_up(size_t x, size_t a) { return (x + a - 1) & ~(a - 1); }

__device__ inline float bf2f(unsigned int u16) {        // u16: low 16 bits hold bf16
    return __uint_as_float(u16 << 16);
}
__device__ inline unsigned short f2bf(float f) {        // round-to-nearest-even
    unsigned int u = __float_as_uint(f);
    u = (u + 0x7fffu + ((u >> 16) & 1u)) >> 16;
    return (unsigned short)u;
}

// ---------------------------------------------------------------------------
__global__ void zero_kernel(int* __restrict__ p, int n) {
    int i = blockIdx.x * 256 + threadIdx.x;
    if (i < n) p[i] = 0;
}

// Edge-encoding detection: int64 storage => all high words of row0 are zero.
__global__ void detect_kernel(const int* __restrict__ e, int* __restrict__ nz, int E) {
    int i = blockIdx.x * blockDim.x + threadIdx.x;
    if (i >= E) return;
    if (e[2 * i + 1] != 0) atomicAdd(nz, 1);
}

__global__ void conv_count_kernel(const int* __restrict__ eraw, const int* __restrict__ nz,
                                  int* __restrict__ src32, int* __restrict__ dst32,
                                  int* __restrict__ cnt, int E) {
    int i = blockIdx.x * blockDim.x + threadIdx.x;
    if (i >= E) return;
    int s, d;
    if (*nz == 0) {  // int64 storage
        const long long* e64 = (const long long*)eraw;
        s = (int)e64[i];
        d = (int)e64[i + E];
    } else {         // int32 storage
        s = eraw[i];
        d = eraw[i + E];
    }
    src32[i] = s;
    dst32[i] = d;
    atomicAdd(&cnt[d], 1);
}

// 3-kernel exclusive scan over cnt[0..n) -> offs[0..n]
__global__ void scan1_kernel(const int* __restrict__ cnt, int* __restrict__ partial,
                             int n, int C) {
    int t = blockIdx.x * 256 + threadIdx.x;  // 0..1023
    int s = 0;
    int base = t * C;
    for (int i = 0; i < C; ++i) {
        int idx = base + i;
        if (idx < n) s += cnt[idx];
    }
    partial[t] = s;
}

__global__ void __launch_bounds__(1024) scan2_kernel(int* __restrict__ partial) {
    __shared__ int sh[1024];
    int t = threadIdx.x;
    sh[t] = partial[t];
    __syncthreads();
    for (int off = 1; off < 1024; off <<= 1) {
        int v = (t >= off) ? sh[t - off] : 0;
        __syncthreads();
        sh[t] += v;
        __syncthreads();
    }
    partial[t] = (t == 0) ? 0 : sh[t - 1];  // exclusive
}

__global__ void scan3_kernel(const int* __restrict__ cnt, const int* __restrict__ partial,
                             int* __restrict__ offs, int n, int C, int E) {
    int t = blockIdx.x * 256 + threadIdx.x;
    int run = partial[t];
    int base = t * C;
    for (int i = 0; i < C; ++i) {
        int idx = base + i;
        if (idx < n) {
            offs[idx] = run;
            run += cnt[idx];
        }
    }
    if (t == 0) offs[n] = E;
}

__global__ void inv_kernel(const int* __restrict__ cnt, float* __restrict__ inv, int n) {
    int i = blockIdx.x * 256 + threadIdx.x;
    if (i < n) inv[i] = 1.0f / (float)max(cnt[i], 1);
}

__global__ void fill_kernel(const int* __restrict__ src32, const int* __restrict__ dst32,
                            const int* __restrict__ offs, int* __restrict__ cursor,
                            int* __restrict__ sorted, int E) {
    int i = blockIdx.x * 256 + threadIdx.x;
    if (i >= E) return;
    int d = dst32[i];
    int p = offs[d] + atomicAdd(&cursor[d], 1);
    sorted[p] = src32[i];
}

// x (fp32) -> bf16 copy, vectorized x4
__global__ void cvt_bf16_kernel(const float* __restrict__ x, unsigned short* __restrict__ xb,
                                int n4) {
    int i = blockIdx.x * 256 + threadIdx.x;
    if (i >= n4) return;
    float4 v = *(const float4*)(x + (size_t)i * 4);
    uint2 o;
    o.x = (unsigned int)f2bf(v.x) | ((unsigned int)f2bf(v.y) << 16);
    o.y = (unsigned int)f2bf(v.z) | ((unsigned int)f2bf(v.w) << 16);
    *(uint2*)(xb + (size_t)i * 4) = o;
}

// ---------------------------------------------------------------------------
// Mean aggregation, one block (128 threads) per destination node.
// ---------------------------------------------------------------------------
// layer 0: fp32 input [N,128] -> bf16 output [N,128]
__global__ void __launch_bounds__(128) agg_mean_f32_kernel(
    const float* __restrict__ X, const int* __restrict__ srt,
    const int* __restrict__ offs, const float* __restrict__ invc,
    unsigned short* __restrict__ out) {
    int nidx = blockIdx.x;
    int beg = offs[nidx], end = offs[nidx + 1];
    float sc = invc[nidx];
    int f = threadIdx.x;
    float acc = 0.f;
    for (int e = beg; e < end; ++e) {
        int s = srt[e];
        acc += X[(size_t)s * 128 + f];
    }
    out[(size_t)nidx * 128 + f] = f2bf(acc * sc);
}

// layers 1/2: bf16 input [N,512] -> bf16 output [N,512], 4 elems/thread
__global__ void __launch_bounds__(128) agg_mean_bf16_kernel(
    const unsigned short* __restrict__ X, const int* __restrict__ srt,
    const int* __restrict__ offs, const float* __restrict__ invc,
    unsigned short* __restrict__ out) {
    int nidx = blockIdx.x;
    int beg = offs[nidx], end = offs[nidx + 1];
    float sc = invc[nidx];
    int t = threadIdx.x;  // 0..127, 4 bf16 each
    float a0 = 0.f, a1 = 0.f, a2 = 0.f, a3 = 0.f;
    for (int e = beg; e < end; ++e) {
        int s = srt[e];
        uint2 v = *(const uint2*)(X + (size_t)s * 512 + t * 4);
        a0 += bf2f(v.x & 0xffffu);
        a1 += bf2f(v.x >> 16);
        a2 += bf2f(v.y & 0xffffu);
        a3 += bf2f(v.y >> 16);
    }
    uint2 o;
    o.x = (unsigned int)f2bf(a0 * sc) | ((unsigned int)f2bf(a1 * sc) << 16);
    o.y = (unsigned int)f2bf(a2 * sc) | ((unsigned int)f2bf(a3 * sc) << 16);
    *(uint2*)(out + (size_t)nidx * 512 + t * 4) = o;
}

// ---------------------------------------------------------------------------
// Fused SAGE layer GEMM: C = relu?( Aagg @ Wl^T + Aself @ Wr^T + bias )
// A: bf16 [M,K] row-major. W: fp32 [N,K] row-major. 128x128 tile, BK=8,
// 8x8 per thread, fp32 FMA compute.
// ---------------------------------------------------------------------------
#define GBM 128
#define GBN 128
#define GBK 8

__global__ void __launch_bounds__(256) sage_gemm_kernel(
    const unsigned short* __restrict__ Aagg, const unsigned short* __restrict__ Aself,
    const float* __restrict__ Wl, const float* __restrict__ Wr,
    const float* __restrict__ bias, void* __restrict__ Cout,
    int M, int N, int K, int relu, int out_bf16) {
    __shared__ float As[GBK][GBM + 4];
    __shared__ float Bs[GBK][GBN + 4];
    const int tx = threadIdx.x & 15;
    const int ty = threadIdx.x >> 4;
    const int m0 = blockIdx.x * GBM;
    const int n0 = blockIdx.y * GBN;

    float acc[8][8];
#pragma unroll
    for (int i = 0; i < 8; ++i)
#pragma unroll
        for (int j = 0; j < 8; ++j) acc[i][j] = 0.f;

    const int r = threadIdx.x >> 1;         // 0..127: tile row staged by this thread
    const int kq = (threadIdx.x & 1) * 4;   // 0 or 4: k-quad within BK=8

    for (int pass = 0; pass < 2; ++pass) {
        const unsigned short* A = pass ? Aself : Aagg;
        const float* W = pass ? Wr : Wl;
        for (int k0 = 0; k0 < K; k0 += GBK) {
            uint2 ua = make_uint2(0u, 0u);
            float4 vb = make_float4(0.f, 0.f, 0.f, 0.f);
            int m = m0 + r;
            if (m < M) ua = *(const uint2*)(A + (size_t)m * K + k0 + kq);
            int n = n0 + r;
            if (n < N) vb = *(const float4*)(W + (size_t)n * K + k0 + kq);
            __syncthreads();  // previous iteration's readers done
            As[kq + 0][r] = bf2f(ua.x & 0xffffu);
            As[kq + 1][r] = bf2f(ua.x >> 16);
            As[kq + 2][r] = bf2f(ua.y & 0xffffu);
            As[kq + 3][r] = bf2f(ua.y >> 16);
            Bs[kq + 0][r] = vb.x; Bs[kq + 1][r] = vb.y;
            Bs[kq + 2][r] = vb.z; Bs[kq + 3][r] = vb.w;
            __syncthreads();
#pragma unroll
            for (int kk = 0; kk < GBK; ++kk) {
                float a[8], b[8];
#pragma unroll
                for (int i = 0; i < 8; ++i) a[i] = As[kk][ty * 8 + i];
#pragma unroll
                for (int j = 0; j < 8; ++j) b[j] = Bs[kk][tx * 8 + j];
#pragma unroll
                for (int i = 0; i < 8; ++i)
#pragma unroll
                    for (int j = 0; j < 8; ++j) acc[i][j] += a[i] * b[j];
            }
        }
    }

    // epilogue: + bias, optional relu
#pragma unroll
    for (int i = 0; i < 8; ++i) {
        int m = m0 + ty * 8 + i;
        if (m >= M) continue;
        int n = n0 + tx * 8;
        float o[8];
#pragma unroll
        for (int j = 0; j < 8; ++j) {
            float v = acc[i][j] + bias[n + j];
            if (relu) v = fmaxf(v, 0.f);
            o[j] = v;
        }
        if (out_bf16) {
            unsigned short* Cb = (unsigned short*)Cout;
            uint4 pk;
            pk.x = (unsigned int)f2bf(o[0]) | ((unsigned int)f2bf(o[1]) << 16);
            pk.y = (unsigned int)f2bf(o[2]) | ((unsigned int)f2bf(o[3]) << 16);
            pk.z = (unsigned int)f2bf(o[4]) | ((unsigned int)f2bf(o[5]) << 16);
            pk.w = (unsigned int)f2bf(o[6]) | ((unsigned int)f2bf(o[7]) << 16);
            *(uint4*)(Cb + (size_t)m * N + n) = pk;
        } else {
            float* Cf = (float*)Cout;
            *(float4*)(Cf + (size_t)m * N + n)     = make_float4(o[0], o[1], o[2], o[3]);
            *(float4*)(Cf + (size_t)m * N + n + 4) = make_float4(o[4], o[5], o[6], o[7]);
        }
    }
}

// ---------------------------------------------------------------------------
extern "C" void kernel_launch(void* const* d_in, const int* in_sizes, int n_in,
                              void* d_out, int out_size, void* d_ws, size_t ws_size,
                              hipStream_t stream) {
    const float* x   = (const float*)d_in[0];
    const int*   e   = (const int*)d_in[1];
    const float* Wl0 = (const float*)d_in[2];
    const float* bl0 = (const float*)d_in[3];
    const float* Wr0 = (const float*)d_in[4];
    const float* Wl1 = (const float*)d_in[5];
    const float* bl1 = (const float*)d_in[6];
    const float* Wr1 = (const float*)d_in[7];
    const float* Wl2 = (const float*)d_in[8];
    const float* bl2 = (const float*)d_in[9];
    const float* Wr2 = (const float*)d_in[10];
    float* out = (float*)d_out;

    const int N = in_sizes[0] / 128;  // 50000 nodes
    const int E = in_sizes[1] / 2;    // 800000 edges

    char* ws = (char*)d_ws;
    size_t off = 0;
    auto alloc = [&](size_t bytes) { size_t o = off; off = align_up(off + bytes, 512); return o; };

    size_t o_nz     = alloc(4);
    size_t o_cnt    = alloc((size_t)N * 4);
    size_t o_cursor = alloc((size_t)N * 4);
    size_t zero_end = off;                       // [0, zero_end) zeroed each call
    size_t o_part   = alloc(1024 * 4);
    size_t o_offs   = alloc((size_t)(N + 1) * 4);
    size_t o_inv    = alloc((size_t)N * 4);
    size_t o_src    = alloc((size_t)E * 4);
    size_t o_dst    = alloc((size_t)E * 4);
    size_t o_sort   = alloc((size_t)E * 4);
    size_t o_xb     = alloc((size_t)N * 128 * 2);   // bf16
    size_t o_agg    = alloc((size_t)N * 512 * 2);   // bf16
    size_t o_h0     = alloc((size_t)N * 512 * 2);   // bf16
    size_t o_h1     = alloc((size_t)N * 512 * 2);   // bf16
    (void)ws_size; (void)n_in; (void)out_size;

    int*            nz     = (int*)(ws + o_nz);
    int*            cnt    = (int*)(ws + o_cnt);
    int*            cursor = (int*)(ws + o_cursor);
    int*            part   = (int*)(ws + o_part);
    int*            offs   = (int*)(ws + o_offs);
    float*          inv    = (float*)(ws + o_inv);
    int*            src32  = (int*)(ws + o_src);
    int*            dst32  = (int*)(ws + o_dst);
    int*            sorted = (int*)(ws + o_sort);
    unsigned short* xb     = (unsigned short*)(ws + o_xb);
    unsigned short* agg    = (unsigned short*)(ws + o_agg);
    unsigned short* h0     = (unsigned short*)(ws + o_h0);
    unsigned short* h1     = (unsigned short*)(ws + o_h1);

    // zero nz/cnt/cursor (workspace is poisoned 0xAA before every call)
    int zn = (int)(zero_end / 4);
    zero_kernel<<<(zn + 255) / 256, 256, 0, stream>>>((int*)ws, zn);

    int eb = (E + 255) / 256;
    detect_kernel<<<eb, 256, 0, stream>>>(e, nz, E);
    conv_count_kernel<<<eb, 256, 0, stream>>>(e, nz, src32, dst32, cnt, E);

    const int C = (N + 1023) / 1024;
    scan1_kernel<<<4, 256, 0, stream>>>(cnt, part, N, C);
    scan2_kernel<<<1, 1024, 0, stream>>>(part);
    scan3_kernel<<<4, 256, 0, stream>>>(cnt, part, offs, N, C, E);
    inv_kernel<<<(N + 255) / 256, 256, 0, stream>>>(cnt, inv, N);
    fill_kernel<<<eb, 256, 0, stream>>>(src32, dst32, offs, cursor, sorted, E);

    // x -> bf16
    int n4 = N * 128 / 4;
    cvt_bf16_kernel<<<(n4 + 255) / 256, 256, 0, stream>>>(x, xb, n4);

    // Layer 0: 128 -> 512, relu, bf16 out
    agg_mean_f32_kernel<<<N, 128, 0, stream>>>(x, sorted, offs, inv, agg);
    dim3 g0((N + GBM - 1) / GBM, 512 / GBN);
    sage_gemm_kernel<<<g0, 256, 0, stream>>>(agg, xb, Wl0, Wr0, bl0, h0, N, 512, 128, 1, 1);

    // Layer 1: 512 -> 512, relu, bf16 out
    agg_mean_bf16_kernel<<<N, 128, 0, stream>>>(h0, sorted, offs, inv, agg);
    dim3 g1((N + GBM - 1) / GBM, 512 / GBN);
    sage_gemm_kernel<<<g1, 256, 0, stream>>>(agg, h0, Wl1, Wr1, bl1, h1, N, 512, 512, 1, 1);

    // Layer 2: 512 -> 256, no relu, fp32 out
    agg_mean_bf16_kernel<<<N, 128, 0, stream>>>(h1, sorted, offs, inv, agg);
    dim3 g2((N + GBM - 1) / GBM, 256 / GBN);
    sage_gemm_kernel<<<g2, 256, 0, stream>>>(agg, h1, Wl2, Wr2, bl2, out, N, 256, 512, 0, 0);
}

// Round 3
// 886.043 us; speedup vs baseline: 2.0792x; 2.0792x over previous
//
#include <hip/hip_runtime.h>
#include <hip/hip_bf16.h>
#include <cstdint>
#include <cstddef>

static inline size_t align_up(size_t x, size_t a) { return (x + a - 1) & ~(a - 1); }

typedef __attribute__((ext_vector_type(4))) float f32x4;
typedef __attribute__((ext_vector_type(8))) short bf16x8;

__device__ inline float bf2f(unsigned int u16) {        // low 16 bits hold bf16
    return __uint_as_float(u16 << 16);
}
__device__ inline unsigned short f2bf(float f) {        // round-to-nearest-even
    unsigned int u = __float_as_uint(f);
    u = (u + 0x7fffu + ((u >> 16) & 1u)) >> 16;
    return (unsigned short)u;
}

#define GLD_LDS(gp, lp) \
    __builtin_amdgcn_global_load_lds( \
        (const __attribute__((address_space(1))) unsigned int*)(gp), \
        (__attribute__((address_space(3))) unsigned int*)(lp), 16, 0, 0)

// ---------------------------------------------------------------------------
__global__ void zero_kernel(int* __restrict__ p, int n) {
    int i = blockIdx.x * 256 + threadIdx.x;
    if (i < n) p[i] = 0;
}

// Edge-encoding detection: int64 storage => all high words of row 0 are zero.
__global__ void detect_kernel(const int* __restrict__ e, int* __restrict__ nz, int E) {
    int i = blockIdx.x * blockDim.x + threadIdx.x;
    if (i >= E) return;
    if (e[2 * i + 1] != 0) atomicAdd(nz, 1);
}

__global__ void conv_count_kernel(const int* __restrict__ eraw, const int* __restrict__ nz,
                                  int* __restrict__ src32, int* __restrict__ dst32,
                                  int* __restrict__ cnt, int E) {
    int i = blockIdx.x * blockDim.x + threadIdx.x;
    if (i >= E) return;
    int s, d;
    if (*nz == 0) {  // int64 storage
        const long long* e64 = (const long long*)eraw;
        s = (int)e64[i];
        d = (int)e64[i + E];
    } else {         // int32 storage
        s = eraw[i];
        d = eraw[i + E];
    }
    src32[i] = s;
    dst32[i] = d;
    atomicAdd(&cnt[d], 1);
}

// 3-kernel exclusive scan over cnt[0..n) -> offs[0..n]
__global__ void scan1_kernel(const int* __restrict__ cnt, int* __restrict__ partial,
                             int n, int C) {
    int t = blockIdx.x * 256 + threadIdx.x;  // 0..1023
    int s = 0;
    int base = t * C;
    for (int i = 0; i < C; ++i) {
        int idx = base + i;
        if (idx < n) s += cnt[idx];
    }
    partial[t] = s;
}

__global__ void __launch_bounds__(1024) scan2_kernel(int* __restrict__ partial) {
    __shared__ int sh[1024];
    int t = threadIdx.x;
    sh[t] = partial[t];
    __syncthreads();
    for (int off = 1; off < 1024; off <<= 1) {
        int v = (t >= off) ? sh[t - off] : 0;
        __syncthreads();
        sh[t] += v;
        __syncthreads();
    }
    partial[t] = (t == 0) ? 0 : sh[t - 1];  // exclusive
}

__global__ void scan3_kernel(const int* __restrict__ cnt, const int* __restrict__ partial,
                             int* __restrict__ offs, int n, int C, int E) {
    int t = blockIdx.x * 256 + threadIdx.x;
    int run = partial[t];
    int base = t * C;
    for (int i = 0; i < C; ++i) {
        int idx = base + i;
        if (idx < n) {
            offs[idx] = run;
            run += cnt[idx];
        }
    }
    if (t == 0) offs[n] = E;
}

__global__ void inv_kernel(const int* __restrict__ cnt, float* __restrict__ inv, int n) {
    int i = blockIdx.x * 256 + threadIdx.x;
    if (i < n) inv[i] = 1.0f / (float)max(cnt[i], 1);
}

__global__ void fill_kernel(const int* __restrict__ src32, const int* __restrict__ dst32,
                            const int* __restrict__ offs, int* __restrict__ cursor,
                            int* __restrict__ sorted, int E) {
    int i = blockIdx.x * 256 + threadIdx.x;
    if (i >= E) return;
    int d = dst32[i];
    int p = offs[d] + atomicAdd(&cursor[d], 1);
    sorted[p] = src32[i];
}

// fp32 -> bf16, vectorized x4
__global__ void cvt_bf16_kernel(const float* __restrict__ x, unsigned short* __restrict__ xb,
                                int n4) {
    int i = blockIdx.x * 256 + threadIdx.x;
    if (i >= n4) return;
    float4 v = *(const float4*)(x + (size_t)i * 4);
    uint2 o;
    o.x = (unsigned int)f2bf(v.x) | ((unsigned int)f2bf(v.y) << 16);
    o.y = (unsigned int)f2bf(v.z) | ((unsigned int)f2bf(v.w) << 16);
    *(uint2*)(xb + (size_t)i * 4) = o;
}

// ---------------------------------------------------------------------------
// Mean aggregation: one WAVE per node, 4 edges unrolled for MLP.
// d=512 bf16: lane covers 8 bf16 (16B). d=128 bf16: lane covers 2 bf16 (4B).
// ---------------------------------------------------------------------------
__global__ void __launch_bounds__(256) agg512_kernel(
    const unsigned short* __restrict__ X, const int* __restrict__ srt,
    const int* __restrict__ offs, const float* __restrict__ invc,
    unsigned short* __restrict__ out, int nNodes) {
    int node = blockIdx.x * 4 + (threadIdx.x >> 6);
    if (node >= nNodes) return;
    int lane = threadIdx.x & 63;
    const unsigned short* xp = X + (size_t)lane * 8;
    int beg = offs[node], end = offs[node + 1];
    float sc = invc[node];
    float a0 = 0.f, a1 = 0.f, a2 = 0.f, a3 = 0.f, a4 = 0.f, a5 = 0.f, a6 = 0.f, a7 = 0.f;
#define ACC8(v)                                \
    do {                                       \
        a0 += bf2f((v).x & 0xffffu);           \
        a1 += bf2f((v).x >> 16);               \
        a2 += bf2f((v).y & 0xffffu);           \
        a3 += bf2f((v).y >> 16);               \
        a4 += bf2f((v).z & 0xffffu);           \
        a5 += bf2f((v).z >> 16);               \
        a6 += bf2f((v).w & 0xffffu);           \
        a7 += bf2f((v).w >> 16);               \
    } while (0)
    int e = beg;
    for (; e + 4 <= end; e += 4) {
        int s0 = srt[e], s1 = srt[e + 1], s2 = srt[e + 2], s3 = srt[e + 3];
        uint4 v0 = *(const uint4*)(xp + (size_t)s0 * 512);
        uint4 v1 = *(const uint4*)(xp + (size_t)s1 * 512);
        uint4 v2 = *(const uint4*)(xp + (size_t)s2 * 512);
        uint4 v3 = *(const uint4*)(xp + (size_t)s3 * 512);
        ACC8(v0); ACC8(v1); ACC8(v2); ACC8(v3);
    }
    for (; e < end; ++e) {
        uint4 v = *(const uint4*)(xp + (size_t)srt[e] * 512);
        ACC8(v);
    }
#undef ACC8
    uint4 o;
    o.x = (unsigned int)f2bf(a0 * sc) | ((unsigned int)f2bf(a1 * sc) << 16);
    o.y = (unsigned int)f2bf(a2 * sc) | ((unsigned int)f2bf(a3 * sc) << 16);
    o.z = (unsigned int)f2bf(a4 * sc) | ((unsigned int)f2bf(a5 * sc) << 16);
    o.w = (unsigned int)f2bf(a6 * sc) | ((unsigned int)f2bf(a7 * sc) << 16);
    *(uint4*)(out + (size_t)node * 512 + lane * 8) = o;
}

__global__ void __launch_bounds__(256) agg128_kernel(
    const unsigned short* __restrict__ X, const int* __restrict__ srt,
    const int* __restrict__ offs, const float* __restrict__ invc,
    unsigned short* __restrict__ out, int nNodes) {
    int node = blockIdx.x * 4 + (threadIdx.x >> 6);
    if (node >= nNodes) return;
    int lane = threadIdx.x & 63;
    const unsigned short* xp = X + (size_t)lane * 2;
    int beg = offs[node], end = offs[node + 1];
    float sc = invc[node];
    float a0 = 0.f, a1 = 0.f;
    int e = beg;
    for (; e + 4 <= end; e += 4) {
        int s0 = srt[e], s1 = srt[e + 1], s2 = srt[e + 2], s3 = srt[e + 3];
        unsigned int v0 = *(const unsigned int*)(xp + (size_t)s0 * 128);
        unsigned int v1 = *(const unsigned int*)(xp + (size_t)s1 * 128);
        unsigned int v2 = *(const unsigned int*)(xp + (size_t)s2 * 128);
        unsigned int v3 = *(const unsigned int*)(xp + (size_t)s3 * 128);
        a0 += bf2f(v0 & 0xffffu) + bf2f(v1 & 0xffffu) + bf2f(v2 & 0xffffu) + bf2f(v3 & 0xffffu);
        a1 += bf2f(v0 >> 16) + bf2f(v1 >> 16) + bf2f(v2 >> 16) + bf2f(v3 >> 16);
    }
    for (; e < end; ++e) {
        unsigned int v = *(const unsigned int*)(xp + (size_t)srt[e] * 128);
        a0 += bf2f(v & 0xffffu);
        a1 += bf2f(v >> 16);
    }
    unsigned int o = (unsigned int)f2bf(a0 * sc) | ((unsigned int)f2bf(a1 * sc) << 16);
    *(unsigned int*)(out + (size_t)node * 128 + lane * 2) = o;
}

// ---------------------------------------------------------------------------
// MFMA SAGE GEMM: C = relu?( Aagg @ Wl^T + Aself @ Wr^T + bias )
// A: bf16 [Mpad,K] row-major (padded, OOB rows garbage-safe). W: bf16 [N,K].
// 128x128 tile, BK=32, 4 waves (2x2), 4x4 16x16x32 MFMA frags per wave.
// global_load_lds width=16 staging, m97 structure.
// ---------------------------------------------------------------------------
__global__ void __launch_bounds__(256) sage_gemm_mfma(
    const unsigned short* __restrict__ Aagg, const unsigned short* __restrict__ Aself,
    const unsigned short* __restrict__ Wlb, const unsigned short* __restrict__ Wrb,
    const float* __restrict__ bias, void* __restrict__ Cout,
    int M, int N, int K, int relu, int out_bf16) {
    __shared__ __attribute__((aligned(16))) unsigned short As[128 * 32];
    __shared__ __attribute__((aligned(16))) unsigned short Bs[128 * 32];
    const int tid = threadIdx.x;
    const int lane = tid & 63;
    const int wave = tid >> 6;
    const int wm = wave >> 1, wn = wave & 1;
    const int m0 = blockIdx.x * 128, n0 = blockIdx.y * 128;

    f32x4 acc[4][4];
#pragma unroll
    for (int i = 0; i < 4; ++i)
#pragma unroll
        for (int j = 0; j < 4; ++j) acc[i][j] = (f32x4){0.f, 0.f, 0.f, 0.f};

    // staging: chunk c (0..7) covers LDS bytes [c*1024, (c+1)*1024) = rows [c*16, c*16+16)
    // this wave stages chunks wave*2 and wave*2+1; lane covers 16B at
    // row = chunk*16 + (lane>>2), kElem = (lane&3)*8
    const int r0 = (wave * 2 + 0) * 16 + (lane >> 2);
    const int r1 = (wave * 2 + 1) * 16 + (lane >> 2);
    const int kE = (lane & 3) * 8;

    // fragment coords
    const int frow = lane & 15;        // m (A) / n (B) within 16-tile
    const int kk = (lane >> 4) * 8;    // k start within BK=32

    for (int pass = 0; pass < 2; ++pass) {
        const unsigned short* A = pass ? Aself : Aagg;
        const unsigned short* W = pass ? Wrb : Wlb;
        for (int k0 = 0; k0 < K; k0 += 32) {
            __syncthreads();  // LDS readers of previous tile done
            GLD_LDS(A + (size_t)(m0 + r0) * K + k0 + kE, &As[(wave * 2 + 0) * 512]);
            GLD_LDS(A + (size_t)(m0 + r1) * K + k0 + kE, &As[(wave * 2 + 1) * 512]);
            GLD_LDS(W + (size_t)(n0 + r0) * K + k0 + kE, &Bs[(wave * 2 + 0) * 512]);
            GLD_LDS(W + (size_t)(n0 + r1) * K + k0 + kE, &Bs[(wave * 2 + 1) * 512]);
            __syncthreads();  // staging complete (barrier drains vmcnt)
            bf16x8 af[4], bf[4];
#pragma unroll
            for (int t = 0; t < 4; ++t)
                af[t] = *(const bf16x8*)&As[(wm * 64 + t * 16 + frow) * 32 + kk];
#pragma unroll
            for (int t = 0; t < 4; ++t)
                bf[t] = *(const bf16x8*)&Bs[(wn * 64 + t * 16 + frow) * 32 + kk];
#pragma unroll
            for (int i = 0; i < 4; ++i)
#pragma unroll
                for (int j = 0; j < 4; ++j)
                    acc[i][j] = __builtin_amdgcn_mfma_f32_16x16x32_bf16(
                        af[i], bf[j], acc[i][j], 0, 0, 0);
        }
    }

    // epilogue: C/D layout col=lane&15, row=(lane>>4)*4+reg
    const int col = lane & 15;
    const int rgrp = (lane >> 4) * 4;
#pragma unroll
    for (int j = 0; j < 4; ++j) {
        int n = n0 + wn * 64 + j * 16 + col;
        float bv = bias[n];
#pragma unroll
        for (int i = 0; i < 4; ++i) {
            int mBase = m0 + wm * 64 + i * 16 + rgrp;
#pragma unroll
            for (int r = 0; r < 4; ++r) {
                int m = mBase + r;
                if (m >= M) continue;
                float v = acc[i][j][r] + bv;
                if (relu) v = fmaxf(v, 0.f);
                if (out_bf16)
                    ((unsigned short*)Cout)[(size_t)m * N + n] = f2bf(v);
                else
                    ((float*)Cout)[(size_t)m * N + n] = v;
            }
        }
    }
}

// ---------------------------------------------------------------------------
extern "C" void kernel_launch(void* const* d_in, const int* in_sizes, int n_in,
                              void* d_out, int out_size, void* d_ws, size_t ws_size,
                              hipStream_t stream) {
    const float* x   = (const float*)d_in[0];
    const int*   e   = (const int*)d_in[1];
    const float* Wl0 = (const float*)d_in[2];
    const float* bl0 = (const float*)d_in[3];
    const float* Wr0 = (const float*)d_in[4];
    const float* Wl1 = (const float*)d_in[5];
    const float* bl1 = (const float*)d_in[6];
    const float* Wr1 = (const float*)d_in[7];
    const float* Wl2 = (const float*)d_in[8];
    const float* bl2 = (const float*)d_in[9];
    const float* Wr2 = (const float*)d_in[10];
    float* out = (float*)d_out;

    const int N = in_sizes[0] / 128;           // 50000 nodes
    const int E = in_sizes[1] / 2;             // 800000 edges
    const int Mpad = ((N + 127) / 128) * 128;  // 50048: GEMM staging never OOB

    char* ws = (char*)d_ws;
    size_t off = 0;
    auto alloc = [&](size_t bytes) { size_t o = off; off = align_up(off + bytes, 512); return o; };

    size_t o_nz     = alloc(4);
    size_t o_cnt    = alloc((size_t)N * 4);
    size_t o_cursor = alloc((size_t)N * 4);
    size_t zero_end = off;                       // [0, zero_end) zeroed each call
    size_t o_part   = alloc(1024 * 4);
    size_t o_offs   = alloc((size_t)(N + 1) * 4);
    size_t o_inv    = alloc((size_t)N * 4);
    size_t o_src    = alloc((size_t)E * 4);
    size_t o_dst    = alloc((size_t)E * 4);
    size_t o_sort   = alloc((size_t)E * 4);
    size_t o_xb     = alloc((size_t)Mpad * 128 * 2);   // bf16 x
    size_t o_agg    = alloc((size_t)Mpad * 512 * 2);   // bf16 agg buffer
    size_t o_h0     = alloc((size_t)Mpad * 512 * 2);   // bf16
    size_t o_h1     = alloc((size_t)Mpad * 512 * 2);   // bf16
    size_t o_wl0    = alloc((size_t)512 * 128 * 2);
    size_t o_wr0    = alloc((size_t)512 * 128 * 2);
    size_t o_wl1    = alloc((size_t)512 * 512 * 2);
    size_t o_wr1    = alloc((size_t)512 * 512 * 2);
    size_t o_wl2    = alloc((size_t)256 * 512 * 2);
    size_t o_wr2    = alloc((size_t)256 * 512 * 2);
    (void)ws_size; (void)n_in; (void)out_size;

    int*            nz     = (int*)(ws + o_nz);
    int*            cnt    = (int*)(ws + o_cnt);
    int*            cursor = (int*)(ws + o_cursor);
    int*            part   = (int*)(ws + o_part);
    int*            offs   = (int*)(ws + o_offs);
    float*          inv    = (float*)(ws + o_inv);
    int*            src32  = (int*)(ws + o_src);
    int*            dst32  = (int*)(ws + o_dst);
    int*            sorted = (int*)(ws + o_sort);
    unsigned short* xb     = (unsigned short*)(ws + o_xb);
    unsigned short* agg    = (unsigned short*)(ws + o_agg);
    unsigned short* h0     = (unsigned short*)(ws + o_h0);
    unsigned short* h1     = (unsigned short*)(ws + o_h1);
    unsigned short* wl0b   = (unsigned short*)(ws + o_wl0);
    unsigned short* wr0b   = (unsigned short*)(ws + o_wr0);
    unsigned short* wl1b   = (unsigned short*)(ws + o_wl1);
    unsigned short* wr1b   = (unsigned short*)(ws + o_wr1);
    unsigned short* wl2b   = (unsigned short*)(ws + o_wl2);
    unsigned short* wr2b   = (unsigned short*)(ws + o_wr2);

    // zero nz/cnt/cursor (ws poisoned 0xAA before every call)
    int zn = (int)(zero_end / 4);
    zero_kernel<<<(zn + 255) / 256, 256, 0, stream>>>((int*)ws, zn);

    int eb = (E + 255) / 256;
    detect_kernel<<<eb, 256, 0, stream>>>(e, nz, E);
    conv_count_kernel<<<eb, 256, 0, stream>>>(e, nz, src32, dst32, cnt, E);

    const int C = (N + 1023) / 1024;
    scan1_kernel<<<4, 256, 0, stream>>>(cnt, part, N, C);
    scan2_kernel<<<1, 1024, 0, stream>>>(part);
    scan3_kernel<<<4, 256, 0, stream>>>(cnt, part, offs, N, C, E);
    inv_kernel<<<(N + 255) / 256, 256, 0, stream>>>(cnt, inv, N);
    fill_kernel<<<eb, 256, 0, stream>>>(src32, dst32, offs, cursor, sorted, E);

    // conversions to bf16
    int n4 = N * 128 / 4;
    cvt_bf16_kernel<<<(n4 + 255) / 256, 256, 0, stream>>>(x, xb, n4);
    cvt_bf16_kernel<<<(512 * 128 / 4 + 255) / 256, 256, 0, stream>>>(Wl0, wl0b, 512 * 128 / 4);
    cvt_bf16_kernel<<<(512 * 128 / 4 + 255) / 256, 256, 0, stream>>>(Wr0, wr0b, 512 * 128 / 4);
    cvt_bf16_kernel<<<(512 * 512 / 4 + 255) / 256, 256, 0, stream>>>(Wl1, wl1b, 512 * 512 / 4);
    cvt_bf16_kernel<<<(512 * 512 / 4 + 255) / 256, 256, 0, stream>>>(Wr1, wr1b, 512 * 512 / 4);
    cvt_bf16_kernel<<<(256 * 512 / 4 + 255) / 256, 256, 0, stream>>>(Wl2, wl2b, 256 * 512 / 4);
    cvt_bf16_kernel<<<(256 * 512 / 4 + 255) / 256, 256, 0, stream>>>(Wr2, wr2b, 256 * 512 / 4);

    const int aggBlocks = (N + 3) / 4;
    const int mBlocks = Mpad / 128;

    // Layer 0: 128 -> 512, relu, bf16 out
    agg128_kernel<<<aggBlocks, 256, 0, stream>>>(xb, sorted, offs, inv, agg, N);
    sage_gemm_mfma<<<dim3(mBlocks, 4), 256, 0, stream>>>(agg, xb, wl0b, wr0b, bl0, h0,
                                                         N, 512, 128, 1, 1);

    // Layer 1: 512 -> 512, relu, bf16 out
    agg512_kernel<<<aggBlocks, 256, 0, stream>>>(h0, sorted, offs, inv, agg, N);
    sage_gemm_mfma<<<dim3(mBlocks, 4), 256, 0, stream>>>(agg, h0, wl1b, wr1b, bl1, h1,
                                                         N, 512, 512, 1, 1);

    // Layer 2: 512 -> 256, no relu, fp32 out
    agg512_kernel<<<aggBlocks, 256, 0, stream>>>(h1, sorted, offs, inv, agg, N);
    sage_gemm_mfma<<<dim3(mBlocks, 2), 256, 0, stream>>>(agg, h1, wl2b, wr2b, bl2, out,
                                                         N, 256, 512, 0, 0);
}

// Round 4
// 748.463 us; speedup vs baseline: 2.4614x; 1.1838x over previous
//
#include <hip/hip_runtime.h>
#include <hip/hip_bf16.h>
#include <cstdint>
#include <cstddef>

static inline size_t align_up(size_t x, size_t a) { return (x + a - 1) & ~(a - 1); }

typedef __attribute__((ext_vector_type(4))) float f32x4;
typedef __attribute__((ext_vector_type(8))) short bf16x8;

__device__ inline float bf2f(unsigned int u16) {        // low 16 bits hold bf16
    return __uint_as_float(u16 << 16);
}
__device__ inline unsigned short f2bf(float f) {        // round-to-nearest-even
    unsigned int u = __float_as_uint(f);
    u = (u + 0x7fffu + ((u >> 16) & 1u)) >> 16;
    return (unsigned short)u;
}

#define GLD_LDS(gp, lp) \
    __builtin_amdgcn_global_load_lds( \
        (const __attribute__((address_space(1))) unsigned int*)(gp), \
        (__attribute__((address_space(3))) unsigned int*)(lp), 16, 0, 0)

// ---------------------------------------------------------------------------
__global__ void zero_kernel(int* __restrict__ p, int n) {
    int i = blockIdx.x * 256 + threadIdx.x;
    if (i < n) p[i] = 0;
}

// Edge-encoding detection, single block. int64 storage => ALL odd 32-bit slots
// (high words) are zero. int32 storage => odd slots are random node ids.
// Sample 4096 odd slots; benign racy store of 1 (no atomics — round-3 profile
// showed 800k same-address atomicAdds cost 144 us of contention).
__global__ void detect_kernel(const int* __restrict__ e, int* __restrict__ nz, int E) {
    int t = threadIdx.x;  // 0..255, one block
    long long stride = (long long)E / 4096;
    if (stride < 1) stride = 1;
    int any = 0;
    for (int k = 0; k < 16; ++k) {
        long long idx = (long long)(t * 16 + k) * stride;
        if (idx < E && e[2 * idx + 1] != 0) any = 1;
    }
    if (any) nz[0] = 1;  // same-value race is benign
}

__global__ void conv_count_kernel(const int* __restrict__ eraw, const int* __restrict__ nz,
                                  int* __restrict__ src32, int* __restrict__ dst32,
                                  int* __restrict__ cnt, int E) {
    int i = blockIdx.x * blockDim.x + threadIdx.x;
    if (i >= E) return;
    int s, d;
    if (*nz == 0) {  // int64 storage
        const long long* e64 = (const long long*)eraw;
        s = (int)e64[i];
        d = (int)e64[i + E];
    } else {         // int32 storage
        s = eraw[i];
        d = eraw[i + E];
    }
    src32[i] = s;
    dst32[i] = d;
    atomicAdd(&cnt[d], 1);
}

// 3-kernel exclusive scan over cnt[0..n) -> offs[0..n]
__global__ void scan1_kernel(const int* __restrict__ cnt, int* __restrict__ partial,
                             int n, int C) {
    int t = blockIdx.x * 256 + threadIdx.x;  // 0..1023
    int s = 0;
    int base = t * C;
    for (int i = 0; i < C; ++i) {
        int idx = base + i;
        if (idx < n) s += cnt[idx];
    }
    partial[t] = s;
}

__global__ void __launch_bounds__(1024) scan2_kernel(int* __restrict__ partial) {
    __shared__ int sh[1024];
    int t = threadIdx.x;
    sh[t] = partial[t];
    __syncthreads();
    for (int off = 1; off < 1024; off <<= 1) {
        int v = (t >= off) ? sh[t - off] : 0;
        __syncthreads();
        sh[t] += v;
        __syncthreads();
    }
    partial[t] = (t == 0) ? 0 : sh[t - 1];  // exclusive
}

__global__ void scan3_kernel(const int* __restrict__ cnt, const int* __restrict__ partial,
                             int* __restrict__ offs, int n, int C, int E) {
    int t = blockIdx.x * 256 + threadIdx.x;
    int run = partial[t];
    int base = t * C;
    for (int i = 0; i < C; ++i) {
        int idx = base + i;
        if (idx < n) {
            offs[idx] = run;
            run += cnt[idx];
        }
    }
    if (t == 0) offs[n] = E;
}

__global__ void inv_kernel(const int* __restrict__ cnt, float* __restrict__ inv, int n) {
    int i = blockIdx.x * 256 + threadIdx.x;
    if (i < n) inv[i] = 1.0f / (float)max(cnt[i], 1);
}

__global__ void fill_kernel(const int* __restrict__ src32, const int* __restrict__ dst32,
                            const int* __restrict__ offs, int* __restrict__ cursor,
                            int* __restrict__ sorted, int E) {
    int i = blockIdx.x * 256 + threadIdx.x;
    if (i >= E) return;
    int d = dst32[i];
    int p = offs[d] + atomicAdd(&cursor[d], 1);
    sorted[p] = src32[i];
}

// fp32 -> bf16, vectorized x4
__global__ void cvt_bf16_kernel(const float* __restrict__ x, unsigned short* __restrict__ xb,
                                int n4) {
    int i = blockIdx.x * 256 + threadIdx.x;
    if (i >= n4) return;
    float4 v = *(const float4*)(x + (size_t)i * 4);
    uint2 o;
    o.x = (unsigned int)f2bf(v.x) | ((unsigned int)f2bf(v.y) << 16);
    o.y = (unsigned int)f2bf(v.z) | ((unsigned int)f2bf(v.w) << 16);
    *(uint2*)(xb + (size_t)i * 4) = o;
}

// ---------------------------------------------------------------------------
// Mean aggregation: one WAVE per node, 4 edges unrolled for MLP.
// d=512 bf16: lane covers 8 bf16 (16B). d=128 bf16: lane covers 2 bf16 (4B).
// ---------------------------------------------------------------------------
__global__ void __launch_bounds__(256) agg512_kernel(
    const unsigned short* __restrict__ X, const int* __restrict__ srt,
    const int* __restrict__ offs, const float* __restrict__ invc,
    unsigned short* __restrict__ out, int nNodes) {
    int node = blockIdx.x * 4 + (threadIdx.x >> 6);
    if (node >= nNodes) return;
    int lane = threadIdx.x & 63;
    const unsigned short* xp = X + (size_t)lane * 8;
    int beg = offs[node], end = offs[node + 1];
    float sc = invc[node];
    float a0 = 0.f, a1 = 0.f, a2 = 0.f, a3 = 0.f, a4 = 0.f, a5 = 0.f, a6 = 0.f, a7 = 0.f;
#define ACC8(v)                                \
    do {                                       \
        a0 += bf2f((v).x & 0xffffu);           \
        a1 += bf2f((v).x >> 16);               \
        a2 += bf2f((v).y & 0xffffu);           \
        a3 += bf2f((v).y >> 16);               \
        a4 += bf2f((v).z & 0xffffu);           \
        a5 += bf2f((v).z >> 16);               \
        a6 += bf2f((v).w & 0xffffu);           \
        a7 += bf2f((v).w >> 16);               \
    } while (0)
    int e = beg;
    for (; e + 4 <= end; e += 4) {
        int s0 = srt[e], s1 = srt[e + 1], s2 = srt[e + 2], s3 = srt[e + 3];
        uint4 v0 = *(const uint4*)(xp + (size_t)s0 * 512);
        uint4 v1 = *(const uint4*)(xp + (size_t)s1 * 512);
        uint4 v2 = *(const uint4*)(xp + (size_t)s2 * 512);
        uint4 v3 = *(const uint4*)(xp + (size_t)s3 * 512);
        ACC8(v0); ACC8(v1); ACC8(v2); ACC8(v3);
    }
    for (; e < end; ++e) {
        uint4 v = *(const uint4*)(xp + (size_t)srt[e] * 512);
        ACC8(v);
    }
#undef ACC8
    uint4 o;
    o.x = (unsigned int)f2bf(a0 * sc) | ((unsigned int)f2bf(a1 * sc) << 16);
    o.y = (unsigned int)f2bf(a2 * sc) | ((unsigned int)f2bf(a3 * sc) << 16);
    o.z = (unsigned int)f2bf(a4 * sc) | ((unsigned int)f2bf(a5 * sc) << 16);
    o.w = (unsigned int)f2bf(a6 * sc) | ((unsigned int)f2bf(a7 * sc) << 16);
    *(uint4*)(out + (size_t)node * 512 + lane * 8) = o;
}

__global__ void __launch_bounds__(256) agg128_kernel(
    const unsigned short* __restrict__ X, const int* __restrict__ srt,
    const int* __restrict__ offs, const float* __restrict__ invc,
    unsigned short* __restrict__ out, int nNodes) {
    int node = blockIdx.x * 4 + (threadIdx.x >> 6);
    if (node >= nNodes) return;
    int lane = threadIdx.x & 63;
    const unsigned short* xp = X + (size_t)lane * 2;
    int beg = offs[node], end = offs[node + 1];
    float sc = invc[node];
    float a0 = 0.f, a1 = 0.f;
    int e = beg;
    for (; e + 4 <= end; e += 4) {
        int s0 = srt[e], s1 = srt[e + 1], s2 = srt[e + 2], s3 = srt[e + 3];
        unsigned int v0 = *(const unsigned int*)(xp + (size_t)s0 * 128);
        unsigned int v1 = *(const unsigned int*)(xp + (size_t)s1 * 128);
        unsigned int v2 = *(const unsigned int*)(xp + (size_t)s2 * 128);
        unsigned int v3 = *(const unsigned int*)(xp + (size_t)s3 * 128);
        a0 += bf2f(v0 & 0xffffu) + bf2f(v1 & 0xffffu) + bf2f(v2 & 0xffffu) + bf2f(v3 & 0xffffu);
        a1 += bf2f(v0 >> 16) + bf2f(v1 >> 16) + bf2f(v2 >> 16) + bf2f(v3 >> 16);
    }
    for (; e < end; ++e) {
        unsigned int v = *(const unsigned int*)(xp + (size_t)srt[e] * 128);
        a0 += bf2f(v & 0xffffu);
        a1 += bf2f(v >> 16);
    }
    unsigned int o = (unsigned int)f2bf(a0 * sc) | ((unsigned int)f2bf(a1 * sc) << 16);
    *(unsigned int*)(out + (size_t)node * 128 + lane * 2) = o;
}

// ---------------------------------------------------------------------------
// MFMA SAGE GEMM: C = relu?( Aagg @ Wl^T + Aself @ Wr^T + bias )
// A: bf16 [Mpad,K] row-major (padded, OOB rows garbage-safe). W: bf16 [N,K].
// 128x128 tile, BK=32, 4 waves (2x2), 4x4 16x16x32 MFMA frags per wave.
// ---------------------------------------------------------------------------
__global__ void __launch_bounds__(256) sage_gemm_mfma(
    const unsigned short* __restrict__ Aagg, const unsigned short* __restrict__ Aself,
    const unsigned short* __restrict__ Wlb, const unsigned short* __restrict__ Wrb,
    const float* __restrict__ bias, void* __restrict__ Cout,
    int M, int N, int K, int relu, int out_bf16) {
    __shared__ __attribute__((aligned(16))) unsigned short As[128 * 32];
    __shared__ __attribute__((aligned(16))) unsigned short Bs[128 * 32];
    const int tid = threadIdx.x;
    const int lane = tid & 63;
    const int wave = tid >> 6;
    const int wm = wave >> 1, wn = wave & 1;
    const int m0 = blockIdx.x * 128, n0 = blockIdx.y * 128;

    f32x4 acc[4][4];
#pragma unroll
    for (int i = 0; i < 4; ++i)
#pragma unroll
        for (int j = 0; j < 4; ++j) acc[i][j] = (f32x4){0.f, 0.f, 0.f, 0.f};

    const int r0 = (wave * 2 + 0) * 16 + (lane >> 2);
    const int r1 = (wave * 2 + 1) * 16 + (lane >> 2);
    const int kE = (lane & 3) * 8;

    const int frow = lane & 15;        // m (A) / n (B) within 16-tile
    const int kk = (lane >> 4) * 8;    // k start within BK=32

    for (int pass = 0; pass < 2; ++pass) {
        const unsigned short* A = pass ? Aself : Aagg;
        const unsigned short* W = pass ? Wrb : Wlb;
        for (int k0 = 0; k0 < K; k0 += 32) {
            __syncthreads();  // LDS readers of previous tile done
            GLD_LDS(A + (size_t)(m0 + r0) * K + k0 + kE, &As[(wave * 2 + 0) * 512]);
            GLD_LDS(A + (size_t)(m0 + r1) * K + k0 + kE, &As[(wave * 2 + 1) * 512]);
            GLD_LDS(W + (size_t)(n0 + r0) * K + k0 + kE, &Bs[(wave * 2 + 0) * 512]);
            GLD_LDS(W + (size_t)(n0 + r1) * K + k0 + kE, &Bs[(wave * 2 + 1) * 512]);
            __syncthreads();  // staging complete (barrier drains vmcnt)
            bf16x8 af[4], bf[4];
#pragma unroll
            for (int t = 0; t < 4; ++t)
                af[t] = *(const bf16x8*)&As[(wm * 64 + t * 16 + frow) * 32 + kk];
#pragma unroll
            for (int t = 0; t < 4; ++t)
                bf[t] = *(const bf16x8*)&Bs[(wn * 64 + t * 16 + frow) * 32 + kk];
#pragma unroll
            for (int i = 0; i < 4; ++i)
#pragma unroll
                for (int j = 0; j < 4; ++j)
                    acc[i][j] = __builtin_amdgcn_mfma_f32_16x16x32_bf16(
                        af[i], bf[j], acc[i][j], 0, 0, 0);
        }
    }

    // epilogue: C/D layout col=lane&15, row=(lane>>4)*4+reg
    const int col = lane & 15;
    const int rgrp = (lane >> 4) * 4;
#pragma unroll
    for (int j = 0; j < 4; ++j) {
        int n = n0 + wn * 64 + j * 16 + col;
        float bv = bias[n];
#pragma unroll
        for (int i = 0; i < 4; ++i) {
            int mBase = m0 + wm * 64 + i * 16 + rgrp;
#pragma unroll
            for (int r = 0; r < 4; ++r) {
                int m = mBase + r;
                if (m >= M) continue;
                float v = acc[i][j][r] + bv;
                if (relu) v = fmaxf(v, 0.f);
                if (out_bf16)
                    ((unsigned short*)Cout)[(size_t)m * N + n] = f2bf(v);
                else
                    ((float*)Cout)[(size_t)m * N + n] = v;
            }
        }
    }
}

// ---------------------------------------------------------------------------
extern "C" void kernel_launch(void* const* d_in, const int* in_sizes, int n_in,
                              void* d_out, int out_size, void* d_ws, size_t ws_size,
                              hipStream_t stream) {
    const float* x   = (const float*)d_in[0];
    const int*   e   = (const int*)d_in[1];
    const float* Wl0 = (const float*)d_in[2];
    const float* bl0 = (const float*)d_in[3];
    const float* Wr0 = (const float*)d_in[4];
    const float* Wl1 = (const float*)d_in[5];
    const float* bl1 = (const float*)d_in[6];
    const float* Wr1 = (const float*)d_in[7];
    const float* Wl2 = (const float*)d_in[8];
    const float* bl2 = (const float*)d_in[9];
    const float* Wr2 = (const float*)d_in[10];
    float* out = (float*)d_out;

    const int N = in_sizes[0] / 128;           // 50000 nodes
    const int E = in_sizes[1] / 2;             // 800000 edges
    const int Mpad = ((N + 127) / 128) * 128;  // 50048: GEMM staging never OOB

    char* ws = (char*)d_ws;
    size_t off = 0;
    auto alloc = [&](size_t bytes) { size_t o = off; off = align_up(off + bytes, 512); return o; };

    size_t o_nz     = alloc(4);
    size_t o_cnt    = alloc((size_t)N * 4);
    size_t o_cursor = alloc((size_t)N * 4);
    size_t zero_end = off;                       // [0, zero_end) zeroed each call
    size_t o_part   = alloc(1024 * 4);
    size_t o_offs   = alloc((size_t)(N + 1) * 4);
    size_t o_inv    = alloc((size_t)N * 4);
    size_t o_src    = alloc((size_t)E * 4);
    size_t o_dst    = alloc((size_t)E * 4);
    size_t o_sort   = alloc((size_t)E * 4);
    size_t o_xb     = alloc((size_t)Mpad * 128 * 2);   // bf16 x
    size_t o_agg    = alloc((size_t)Mpad * 512 * 2);   // bf16 agg buffer
    size_t o_h0     = alloc((size_t)Mpad * 512 * 2);   // bf16
    size_t o_h1     = alloc((size_t)Mpad * 512 * 2);   // bf16
    size_t o_wl0    = alloc((size_t)512 * 128 * 2);
    size_t o_wr0    = alloc((size_t)512 * 128 * 2);
    size_t o_wl1    = alloc((size_t)512 * 512 * 2);
    size_t o_wr1    = alloc((size_t)512 * 512 * 2);
    size_t o_wl2    = alloc((size_t)256 * 512 * 2);
    size_t o_wr2    = alloc((size_t)256 * 512 * 2);
    (void)ws_size; (void)n_in; (void)out_size;

    int*            nz     = (int*)(ws + o_nz);
    int*            cnt    = (int*)(ws + o_cnt);
    int*            cursor = (int*)(ws + o_cursor);
    int*            part   = (int*)(ws + o_part);
    int*            offs   = (int*)(ws + o_offs);
    float*          inv    = (float*)(ws + o_inv);
    int*            src32  = (int*)(ws + o_src);
    int*            dst32  = (int*)(ws + o_dst);
    int*            sorted = (int*)(ws + o_sort);
    unsigned short* xb     = (unsigned short*)(ws + o_xb);
    unsigned short* agg    = (unsigned short*)(ws + o_agg);
    unsigned short* h0     = (unsigned short*)(ws + o_h0);
    unsigned short* h1     = (unsigned short*)(ws + o_h1);
    unsigned short* wl0b   = (unsigned short*)(ws + o_wl0);
    unsigned short* wr0b   = (unsigned short*)(ws + o_wr0);
    unsigned short* wl1b   = (unsigned short*)(ws + o_wl1);
    unsigned short* wr1b   = (unsigned short*)(ws + o_wr1);
    unsigned short* wl2b   = (unsigned short*)(ws + o_wl2);
    unsigned short* wr2b   = (unsigned short*)(ws + o_wr2);

    // zero nz/cnt/cursor (ws poisoned 0xAA before every call)
    int zn = (int)(zero_end / 4);
    zero_kernel<<<(zn + 255) / 256, 256, 0, stream>>>((int*)ws, zn);

    int eb = (E + 255) / 256;
    detect_kernel<<<1, 256, 0, stream>>>(e, nz, E);
    conv_count_kernel<<<eb, 256, 0, stream>>>(e, nz, src32, dst32, cnt, E);

    const int C = (N + 1023) / 1024;
    scan1_kernel<<<4, 256, 0, stream>>>(cnt, part, N, C);
    scan2_kernel<<<1, 1024, 0, stream>>>(part);
    scan3_kernel<<<4, 256, 0, stream>>>(cnt, part, offs, N, C, E);
    inv_kernel<<<(N + 255) / 256, 256, 0, stream>>>(cnt, inv, N);
    fill_kernel<<<eb, 256, 0, stream>>>(src32, dst32, offs, cursor, sorted, E);

    // conversions to bf16
    int n4 = N * 128 / 4;
    cvt_bf16_kernel<<<(n4 + 255) / 256, 256, 0, stream>>>(x, xb, n4);
    cvt_bf16_kernel<<<(512 * 128 / 4 + 255) / 256, 256, 0, stream>>>(Wl0, wl0b, 512 * 128 / 4);
    cvt_bf16_kernel<<<(512 * 128 / 4 + 255) / 256, 256, 0, stream>>>(Wr0, wr0b, 512 * 128 / 4);
    cvt_bf16_kernel<<<(512 * 512 / 4 + 255) / 256, 256, 0, stream>>>(Wl1, wl1b, 512 * 512 / 4);
    cvt_bf16_kernel<<<(512 * 512 / 4 + 255) / 256, 256, 0, stream>>>(Wr1, wr1b, 512 * 512 / 4);
    cvt_bf16_kernel<<<(256 * 512 / 4 + 255) / 256, 256, 0, stream>>>(Wl2, wl2b, 256 * 512 / 4);
    cvt_bf16_kernel<<<(256 * 512 / 4 + 255) / 256, 256, 0, stream>>>(Wr2, wr2b, 256 * 512 / 4);

    const int aggBlocks = (N + 3) / 4;
    const int mBlocks = Mpad / 128;

    // Layer 0: 128 -> 512, relu, bf16 out
    agg128_kernel<<<aggBlocks, 256, 0, stream>>>(xb, sorted, offs, inv, agg, N);
    sage_gemm_mfma<<<dim3(mBlocks, 4), 256, 0, stream>>>(agg, xb, wl0b, wr0b, bl0, h0,
                                                         N, 512, 128, 1, 1);

    // Layer 1: 512 -> 512, relu, bf16 out
    agg512_kernel<<<aggBlocks, 256, 0, stream>>>(h0, sorted, offs, inv, agg, N);
    sage_gemm_mfma<<<dim3(mBlocks, 4), 256, 0, stream>>>(agg, h0, wl1b, wr1b, bl1, h1,
                                                         N, 512, 512, 1, 1);

    // Layer 2: 512 -> 256, no relu, fp32 out
    agg512_kernel<<<aggBlocks, 256, 0, stream>>>(h1, sorted, offs, inv, agg, N);
    sage_gemm_mfma<<<dim3(mBlocks, 2), 256, 0, stream>>>(agg, h1, wl2b, wr2b, bl2, out,
                                                         N, 256, 512, 0, 0);
}

// Round 5
// 732.943 us; speedup vs baseline: 2.5135x; 1.0212x over previous
//
#include <hip/hip_runtime.h>
#include <hip/hip_bf16.h>
#include <cstdint>
#include <cstddef>

static inline size_t align_up(size_t x, size_t a) { return (x + a - 1) & ~(a - 1); }

typedef __attribute__((ext_vector_type(4))) float f32x4;
typedef __attribute__((ext_vector_type(8))) short bf16x8;

__device__ inline float bf2f(unsigned int u16) {        // low 16 bits hold bf16
    return __uint_as_float(u16 << 16);
}
__device__ inline unsigned short f2bf(float f) {        // round-to-nearest-even
    unsigned int u = __float_as_uint(f);
    u = (u + 0x7fffu + ((u >> 16) & 1u)) >> 16;
    return (unsigned short)u;
}

#define GLD_LDS(gp, lp) \
    __builtin_amdgcn_global_load_lds( \
        (const __attribute__((address_space(1))) unsigned int*)(gp), \
        (__attribute__((address_space(3))) unsigned int*)(lp), 16, 0, 0)

// ---------------------------------------------------------------------------
__global__ void zero_kernel(int* __restrict__ p, int n) {
    int i = blockIdx.x * 256 + threadIdx.x;
    if (i < n) p[i] = 0;
}

// Edge-encoding detection, single block, sampled, no atomics.
__global__ void detect_kernel(const int* __restrict__ e, int* __restrict__ nz, int E) {
    int t = threadIdx.x;  // 0..255, one block
    long long stride = (long long)E / 4096;
    if (stride < 1) stride = 1;
    int any = 0;
    for (int k = 0; k < 16; ++k) {
        long long idx = (long long)(t * 16 + k) * stride;
        if (idx < E && e[2 * idx + 1] != 0) any = 1;
    }
    if (any) nz[0] = 1;  // same-value race is benign
}

__global__ void conv_count_kernel(const int* __restrict__ eraw, const int* __restrict__ nz,
                                  int* __restrict__ src32, int* __restrict__ dst32,
                                  int* __restrict__ cnt, int E) {
    int i = blockIdx.x * blockDim.x + threadIdx.x;
    if (i >= E) return;
    int s, d;
    if (*nz == 0) {  // int64 storage
        const long long* e64 = (const long long*)eraw;
        s = (int)e64[i];
        d = (int)e64[i + E];
    } else {         // int32 storage
        s = eraw[i];
        d = eraw[i + E];
    }
    src32[i] = s;
    dst32[i] = d;
    atomicAdd(&cnt[d], 1);
}

// 3-kernel exclusive scan over cnt[0..n) -> offs[0..n]
__global__ void scan1_kernel(const int* __restrict__ cnt, int* __restrict__ partial,
                             int n, int C) {
    int t = blockIdx.x * 256 + threadIdx.x;  // 0..1023
    int s = 0;
    int base = t * C;
    for (int i = 0; i < C; ++i) {
        int idx = base + i;
        if (idx < n) s += cnt[idx];
    }
    partial[t] = s;
}

__global__ void __launch_bounds__(1024) scan2_kernel(int* __restrict__ partial) {
    __shared__ int sh[1024];
    int t = threadIdx.x;
    sh[t] = partial[t];
    __syncthreads();
    for (int off = 1; off < 1024; off <<= 1) {
        int v = (t >= off) ? sh[t - off] : 0;
        __syncthreads();
        sh[t] += v;
        __syncthreads();
    }
    partial[t] = (t == 0) ? 0 : sh[t - 1];  // exclusive
}

__global__ void scan3_kernel(const int* __restrict__ cnt, const int* __restrict__ partial,
                             int* __restrict__ offs, int n, int C, int E) {
    int t = blockIdx.x * 256 + threadIdx.x;
    int run = partial[t];
    int base = t * C;
    for (int i = 0; i < C; ++i) {
        int idx = base + i;
        if (idx < n) {
            offs[idx] = run;
            run += cnt[idx];
        }
    }
    if (t == 0) offs[n] = E;
}

__global__ void inv_kernel(const int* __restrict__ cnt, float* __restrict__ inv, int n) {
    int i = blockIdx.x * 256 + threadIdx.x;
    if (i < n) inv[i] = 1.0f / (float)max(cnt[i], 1);
}

__global__ void fill_kernel(const int* __restrict__ src32, const int* __restrict__ dst32,
                            const int* __restrict__ offs, int* __restrict__ cursor,
                            int* __restrict__ sorted, int E) {
    int i = blockIdx.x * 256 + threadIdx.x;
    if (i >= E) return;
    int d = dst32[i];
    int p = offs[d] + atomicAdd(&cursor[d], 1);
    sorted[p] = src32[i];
}

// fp32 -> bf16, vectorized x4
__global__ void cvt_bf16_kernel(const float* __restrict__ x, unsigned short* __restrict__ xb,
                                int n4) {
    int i = blockIdx.x * 256 + threadIdx.x;
    if (i >= n4) return;
    float4 v = *(const float4*)(x + (size_t)i * 4);
    uint2 o;
    o.x = (unsigned int)f2bf(v.x) | ((unsigned int)f2bf(v.y) << 16);
    o.y = (unsigned int)f2bf(v.z) | ((unsigned int)f2bf(v.w) << 16);
    *(uint2*)(xb + (size_t)i * 4) = o;
}

// ---------------------------------------------------------------------------
// Mean aggregation: one WAVE per node, 4 edges unrolled for MLP.
// ---------------------------------------------------------------------------
__global__ void __launch_bounds__(256) agg512_kernel(
    const unsigned short* __restrict__ X, const int* __restrict__ srt,
    const int* __restrict__ offs, const float* __restrict__ invc,
    unsigned short* __restrict__ out, int nNodes) {
    int node = blockIdx.x * 4 + (threadIdx.x >> 6);
    if (node >= nNodes) return;
    int lane = threadIdx.x & 63;
    const unsigned short* xp = X + (size_t)lane * 8;
    int beg = offs[node], end = offs[node + 1];
    float sc = invc[node];
    float a0 = 0.f, a1 = 0.f, a2 = 0.f, a3 = 0.f, a4 = 0.f, a5 = 0.f, a6 = 0.f, a7 = 0.f;
#define ACC8(v)                                \
    do {                                       \
        a0 += bf2f((v).x & 0xffffu);           \
        a1 += bf2f((v).x >> 16);               \
        a2 += bf2f((v).y & 0xffffu);           \
        a3 += bf2f((v).y >> 16);               \
        a4 += bf2f((v).z & 0xffffu);           \
        a5 += bf2f((v).z >> 16);               \
        a6 += bf2f((v).w & 0xffffu);           \
        a7 += bf2f((v).w >> 16);               \
    } while (0)
    int e = beg;
    for (; e + 4 <= end; e += 4) {
        int s0 = srt[e], s1 = srt[e + 1], s2 = srt[e + 2], s3 = srt[e + 3];
        uint4 v0 = *(const uint4*)(xp + (size_t)s0 * 512);
        uint4 v1 = *(const uint4*)(xp + (size_t)s1 * 512);
        uint4 v2 = *(const uint4*)(xp + (size_t)s2 * 512);
        uint4 v3 = *(const uint4*)(xp + (size_t)s3 * 512);
        ACC8(v0); ACC8(v1); ACC8(v2); ACC8(v3);
    }
    for (; e < end; ++e) {
        uint4 v = *(const uint4*)(xp + (size_t)srt[e] * 512);
        ACC8(v);
    }
#undef ACC8
    uint4 o;
    o.x = (unsigned int)f2bf(a0 * sc) | ((unsigned int)f2bf(a1 * sc) << 16);
    o.y = (unsigned int)f2bf(a2 * sc) | ((unsigned int)f2bf(a3 * sc) << 16);
    o.z = (unsigned int)f2bf(a4 * sc) | ((unsigned int)f2bf(a5 * sc) << 16);
    o.w = (unsigned int)f2bf(a6 * sc) | ((unsigned int)f2bf(a7 * sc) << 16);
    *(uint4*)(out + (size_t)node * 512 + lane * 8) = o;
}

__global__ void __launch_bounds__(256) agg128_kernel(
    const unsigned short* __restrict__ X, const int* __restrict__ srt,
    const int* __restrict__ offs, const float* __restrict__ invc,
    unsigned short* __restrict__ out, int nNodes) {
    int node = blockIdx.x * 4 + (threadIdx.x >> 6);
    if (node >= nNodes) return;
    int lane = threadIdx.x & 63;
    const unsigned short* xp = X + (size_t)lane * 2;
    int beg = offs[node], end = offs[node + 1];
    float sc = invc[node];
    float a0 = 0.f, a1 = 0.f;
    int e = beg;
    for (; e + 4 <= end; e += 4) {
        int s0 = srt[e], s1 = srt[e + 1], s2 = srt[e + 2], s3 = srt[e + 3];
        unsigned int v0 = *(const unsigned int*)(xp + (size_t)s0 * 128);
        unsigned int v1 = *(const unsigned int*)(xp + (size_t)s1 * 128);
        unsigned int v2 = *(const unsigned int*)(xp + (size_t)s2 * 128);
        unsigned int v3 = *(const unsigned int*)(xp + (size_t)s3 * 128);
        a0 += bf2f(v0 & 0xffffu) + bf2f(v1 & 0xffffu) + bf2f(v2 & 0xffffu) + bf2f(v3 & 0xffffu);
        a1 += bf2f(v0 >> 16) + bf2f(v1 >> 16) + bf2f(v2 >> 16) + bf2f(v3 >> 16);
    }
    for (; e < end; ++e) {
        unsigned int v = *(const unsigned int*)(xp + (size_t)srt[e] * 128);
        a0 += bf2f(v & 0xffffu);
        a1 += bf2f(v >> 16);
    }
    unsigned int o = (unsigned int)f2bf(a0 * sc) | ((unsigned int)f2bf(a1 * sc) << 16);
    *(unsigned int*)(out + (size_t)node * 128 + lane * 2) = o;
}

// ---------------------------------------------------------------------------
// MFMA SAGE GEMM, wide-N tile: C = relu?( Aagg @ Wl^T + Aself @ Wr^T + bias )
// Tile 128(M) x 256(N), BK=32. 4 waves, each owns 64x128 (4x8 16x16x32 frags).
// Rationale (round-4 counters): BM=BN=128 re-read A 4x -> FETCH 206 MB,
// 420 TF memory-bound. BN=256 + n-chunk in blockIdx.x (adjacent dispatch)
// cuts HBM A-traffic to ~1x; W is L2-resident.
// ---------------------------------------------------------------------------
__global__ void __launch_bounds__(256, 2) sage_gemm_mfma(
    const unsigned short* __restrict__ Aagg, const unsigned short* __restrict__ Aself,
    const unsigned short* __restrict__ Wlb, const unsigned short* __restrict__ Wrb,
    const float* __restrict__ bias, void* __restrict__ Cout,
    int M, int N, int K, int relu, int out_bf16) {
    __shared__ __attribute__((aligned(16))) unsigned short As[128 * 32];  //  8 KB
    __shared__ __attribute__((aligned(16))) unsigned short Bs[256 * 32];  // 16 KB
    const int tid = threadIdx.x;
    const int lane = tid & 63;
    const int wave = tid >> 6;
    const int wm = wave >> 1, wn = wave & 1;          // 2x2 wave grid
    const int m0 = blockIdx.y * 128, n0 = blockIdx.x * 256;

    f32x4 acc[4][8];
#pragma unroll
    for (int i = 0; i < 4; ++i)
#pragma unroll
        for (int j = 0; j < 8; ++j) acc[i][j] = (f32x4){0.f, 0.f, 0.f, 0.f};

    // staging: row covered by (chunk, wave, lane>>2); lane covers 16B at
    // kElem=(lane&3)*8. LDS dst offset = base(chunk,wave) + lane*16 (wave-uniform+lane*16).
    const int srow = wave * 16 + (lane >> 2);
    const int kE = (lane & 3) * 8;

    // fragment coords
    const int frow = lane & 15;        // m (A) / n (B) within 16-tile
    const int kk = (lane >> 4) * 8;    // k start within BK=32

    for (int pass = 0; pass < 2; ++pass) {
        const unsigned short* A = pass ? Aself : Aagg;
        const unsigned short* W = pass ? Wrb : Wlb;
        for (int k0 = 0; k0 < K; k0 += 32) {
            __syncthreads();  // LDS readers of previous tile done
            // A-tile: 128 rows, chunks c=0,1 -> rows c*64 + srow
            GLD_LDS(A + (size_t)(m0 + 0 * 64 + srow) * K + k0 + kE, &As[0 * 2048 + wave * 512]);
            GLD_LDS(A + (size_t)(m0 + 1 * 64 + srow) * K + k0 + kE, &As[1 * 2048 + wave * 512]);
            // W-tile: 256 rows, chunks c=0..3
            GLD_LDS(W + (size_t)(n0 + 0 * 64 + srow) * K + k0 + kE, &Bs[0 * 2048 + wave * 512]);
            GLD_LDS(W + (size_t)(n0 + 1 * 64 + srow) * K + k0 + kE, &Bs[1 * 2048 + wave * 512]);
            GLD_LDS(W + (size_t)(n0 + 2 * 64 + srow) * K + k0 + kE, &Bs[2 * 2048 + wave * 512]);
            GLD_LDS(W + (size_t)(n0 + 3 * 64 + srow) * K + k0 + kE, &Bs[3 * 2048 + wave * 512]);
            __syncthreads();  // staging complete (barrier drains vmcnt)
            bf16x8 af[4], bfr[8];
#pragma unroll
            for (int t = 0; t < 4; ++t)
                af[t] = *(const bf16x8*)&As[(wm * 64 + t * 16 + frow) * 32 + kk];
#pragma unroll
            for (int t = 0; t < 8; ++t)
                bfr[t] = *(const bf16x8*)&Bs[(wn * 128 + t * 16 + frow) * 32 + kk];
#pragma unroll
            for (int i = 0; i < 4; ++i)
#pragma unroll
                for (int j = 0; j < 8; ++j)
                    acc[i][j] = __builtin_amdgcn_mfma_f32_16x16x32_bf16(
                        af[i], bfr[j], acc[i][j], 0, 0, 0);
        }
    }

    // epilogue: C/D layout col=lane&15, row=(lane>>4)*4+reg
    const int col = lane & 15;
    const int rgrp = (lane >> 4) * 4;
#pragma unroll
    for (int j = 0; j < 8; ++j) {
        int n = n0 + wn * 128 + j * 16 + col;
        float bv = bias[n];
#pragma unroll
        for (int i = 0; i < 4; ++i) {
            int mBase = m0 + wm * 64 + i * 16 + rgrp;
#pragma unroll
            for (int r = 0; r < 4; ++r) {
                int m = mBase + r;
                if (m >= M) continue;
                float v = acc[i][j][r] + bv;
                if (relu) v = fmaxf(v, 0.f);
                if (out_bf16)
                    ((unsigned short*)Cout)[(size_t)m * N + n] = f2bf(v);
                else
                    ((float*)Cout)[(size_t)m * N + n] = v;
            }
        }
    }
}

// ---------------------------------------------------------------------------
extern "C" void kernel_launch(void* const* d_in, const int* in_sizes, int n_in,
                              void* d_out, int out_size, void* d_ws, size_t ws_size,
                              hipStream_t stream) {
    const float* x   = (const float*)d_in[0];
    const int*   e   = (const int*)d_in[1];
    const float* Wl0 = (const float*)d_in[2];
    const float* bl0 = (const float*)d_in[3];
    const float* Wr0 = (const float*)d_in[4];
    const float* Wl1 = (const float*)d_in[5];
    const float* bl1 = (const float*)d_in[6];
    const float* Wr1 = (const float*)d_in[7];
    const float* Wl2 = (const float*)d_in[8];
    const float* bl2 = (const float*)d_in[9];
    const float* Wr2 = (const float*)d_in[10];
    float* out = (float*)d_out;

    const int N = in_sizes[0] / 128;           // 50000 nodes
    const int E = in_sizes[1] / 2;             // 800000 edges
    const int Mpad = ((N + 127) / 128) * 128;  // 50048: GEMM staging never OOB

    char* ws = (char*)d_ws;
    size_t off = 0;
    auto alloc = [&](size_t bytes) { size_t o = off; off = align_up(off + bytes, 512); return o; };

    size_t o_nz     = alloc(4);
    size_t o_cnt    = alloc((size_t)N * 4);
    size_t o_cursor = alloc((size_t)N * 4);
    size_t zero_end = off;                       // [0, zero_end) zeroed each call
    size_t o_part   = alloc(1024 * 4);
    size_t o_offs   = alloc((size_t)(N + 1) * 4);
    size_t o_inv    = alloc((size_t)N * 4);
    size_t o_src    = alloc((size_t)E * 4);
    size_t o_dst    = alloc((size_t)E * 4);
    size_t o_sort   = alloc((size_t)E * 4);
    size_t o_xb     = alloc((size_t)Mpad * 128 * 2);   // bf16 x
    size_t o_agg    = alloc((size_t)Mpad * 512 * 2);   // bf16 agg buffer
    size_t o_h0     = alloc((size_t)Mpad * 512 * 2);   // bf16
    size_t o_h1     = alloc((size_t)Mpad * 512 * 2);   // bf16
    size_t o_wl0    = alloc((size_t)512 * 128 * 2);
    size_t o_wr0    = alloc((size_t)512 * 128 * 2);
    size_t o_wl1    = alloc((size_t)512 * 512 * 2);
    size_t o_wr1    = alloc((size_t)512 * 512 * 2);
    size_t o_wl2    = alloc((size_t)256 * 512 * 2);
    size_t o_wr2    = alloc((size_t)256 * 512 * 2);
    (void)ws_size; (void)n_in; (void)out_size;

    int*            nz     = (int*)(ws + o_nz);
    int*            cnt    = (int*)(ws + o_cnt);
    int*            cursor = (int*)(ws + o_cursor);
    int*            part   = (int*)(ws + o_part);
    int*            offs   = (int*)(ws + o_offs);
    float*          inv    = (float*)(ws + o_inv);
    int*            src32  = (int*)(ws + o_src);
    int*            dst32  = (int*)(ws + o_dst);
    int*            sorted = (int*)(ws + o_sort);
    unsigned short* xb     = (unsigned short*)(ws + o_xb);
    unsigned short* agg    = (unsigned short*)(ws + o_agg);
    unsigned short* h0     = (unsigned short*)(ws + o_h0);
    unsigned short* h1     = (unsigned short*)(ws + o_h1);
    unsigned short* wl0b   = (unsigned short*)(ws + o_wl0);
    unsigned short* wr0b   = (unsigned short*)(ws + o_wr0);
    unsigned short* wl1b   = (unsigned short*)(ws + o_wl1);
    unsigned short* wr1b   = (unsigned short*)(ws + o_wr1);
    unsigned short* wl2b   = (unsigned short*)(ws + o_wl2);
    unsigned short* wr2b   = (unsigned short*)(ws + o_wr2);

    // zero nz/cnt/cursor (ws poisoned 0xAA before every call)
    int zn = (int)(zero_end / 4);
    zero_kernel<<<(zn + 255) / 256, 256, 0, stream>>>((int*)ws, zn);

    int eb = (E + 255) / 256;
    detect_kernel<<<1, 256, 0, stream>>>(e, nz, E);
    conv_count_kernel<<<eb, 256, 0, stream>>>(e, nz, src32, dst32, cnt, E);

    const int C = (N + 1023) / 1024;
    scan1_kernel<<<4, 256, 0, stream>>>(cnt, part, N, C);
    scan2_kernel<<<1, 1024, 0, stream>>>(part);
    scan3_kernel<<<4, 256, 0, stream>>>(cnt, part, offs, N, C, E);
    inv_kernel<<<(N + 255) / 256, 256, 0, stream>>>(cnt, inv, N);
    fill_kernel<<<eb, 256, 0, stream>>>(src32, dst32, offs, cursor, sorted, E);

    // conversions to bf16
    int n4 = N * 128 / 4;
    cvt_bf16_kernel<<<(n4 + 255) / 256, 256, 0, stream>>>(x, xb, n4);
    cvt_bf16_kernel<<<(512 * 128 / 4 + 255) / 256, 256, 0, stream>>>(Wl0, wl0b, 512 * 128 / 4);
    cvt_bf16_kernel<<<(512 * 128 / 4 + 255) / 256, 256, 0, stream>>>(Wr0, wr0b, 512 * 128 / 4);
    cvt_bf16_kernel<<<(512 * 512 / 4 + 255) / 256, 256, 0, stream>>>(Wl1, wl1b, 512 * 512 / 4);
    cvt_bf16_kernel<<<(512 * 512 / 4 + 255) / 256, 256, 0, stream>>>(Wr1, wr1b, 512 * 512 / 4);
    cvt_bf16_kernel<<<(256 * 512 / 4 + 255) / 256, 256, 0, stream>>>(Wl2, wl2b, 256 * 512 / 4);
    cvt_bf16_kernel<<<(256 * 512 / 4 + 255) / 256, 256, 0, stream>>>(Wr2, wr2b, 256 * 512 / 4);

    const int aggBlocks = (N + 3) / 4;
    const int mBlocks = Mpad / 128;

    // Layer 0: 128 -> 512, relu, bf16 out
    agg128_kernel<<<aggBlocks, 256, 0, stream>>>(xb, sorted, offs, inv, agg, N);
    sage_gemm_mfma<<<dim3(2, mBlocks), 256, 0, stream>>>(agg, xb, wl0b, wr0b, bl0, h0,
                                                         N, 512, 128, 1, 1);

    // Layer 1: 512 -> 512, relu, bf16 out
    agg512_kernel<<<aggBlocks, 256, 0, stream>>>(h0, sorted, offs, inv, agg, N);
    sage_gemm_mfma<<<dim3(2, mBlocks), 256, 0, stream>>>(agg, h0, wl1b, wr1b, bl1, h1,
                                                         N, 512, 512, 1, 1);

    // Layer 2: 512 -> 256, no relu, fp32 out
    agg512_kernel<<<aggBlocks, 256, 0, stream>>>(h1, sorted, offs, inv, agg, N);
    sage_gemm_mfma<<<dim3(1, mBlocks), 256, 0, stream>>>(agg, h1, wl2b, wr2b, bl2, out,
                                                         N, 256, 512, 0, 0);
}